// Round 12
// baseline (73.382 us; speedup 1.0000x reference)
//
#include <hip/hip_runtime.h>
#include <hip/hip_bf16.h>

typedef short short8 __attribute__((ext_vector_type(8)));
typedef float f32x4 __attribute__((ext_vector_type(4)));

#define NPREP 64

__device__ inline unsigned short f2bf(float f) {
    unsigned u = __builtin_bit_cast(unsigned, f);
    u += 0x7FFFu + ((u >> 16) & 1u);          // round-to-nearest-even
    return (unsigned short)(u >> 16);
}

// one thread's slice of the B-fragment prep (g = 0..16383)
__device__ inline void prep_slice(int g, const float* __restrict__ Wv,
                                  const float* __restrict__ bv,
                                  unsigned short* __restrict__ Bf,
                                  float* __restrict__ bm)
{
    const int fi = g >> 9;                          // fragment index 0..31
    const int lane = (g >> 3) & 63;
    const int j = g & 7;
    const int ct = fi >> 3, kc = fi & 7;
    const int d = ct * 16 + (lane & 15);
    const int c = kc * 32 + (lane >> 4) * 8 + j;
    const float s = 0.25f * (Wv[(size_t)d * 256 + c] +
                             Wv[(size_t)(64 + d) * 256 + c] +
                             Wv[(size_t)(128 + d) * 256 + c] +
                             Wv[(size_t)(192 + d) * 256 + c]);
    Bf[g] = f2bf(s);
    if (g < 64)
        bm[g] = 0.25f * (bv[g] + bv[64 + g] + bv[128 + g] + bv[192 + g]);
}

// fallback prep kernel (only used if grid < NPREP blocks)
__global__ __launch_bounds__(256)
void k_prep(const float* __restrict__ Wv, const float* __restrict__ bv,
            unsigned short* __restrict__ Bf, float* __restrict__ bm,
            unsigned* __restrict__ flag)
{
    prep_slice(blockIdx.x * 256 + threadIdx.x, Wv, bv, Bf, bm);
    __threadfence();
    __syncthreads();
    if (threadIdx.x == 0)
        __hip_atomic_fetch_add(flag, 1u, __ATOMIC_RELEASE, __HIP_MEMORY_SCOPE_AGENT);
}

// ---------------------------------------------------------------------------
// single-dispatch main: out[n][d] = sum_c X[n][c]*Wm[d][c] + bm[d]
// Blocks < npre build Bf (once per grid, 1/64 each) then join the GEMM.
// All blocks: issue X loads FIRST (HBM ramp overlaps prep), spin on a
// device-scope acquire flag until Bf is published, then MFMA + R9 epilogue.
// ---------------------------------------------------------------------------
__global__ __launch_bounds__(256)
void k_main(const float* __restrict__ X, const float* __restrict__ Wv,
            const float* __restrict__ bv, unsigned short* __restrict__ Bf,
            float* __restrict__ bm, unsigned* __restrict__ flag,
            float* __restrict__ out, int N, int npre)
{
    __shared__ float Xt[4][16 * 68];                // 17 KB epilogue tiles

    const int t = threadIdx.x;
    const int wave = t >> 6, lane = t & 63;
    const int col_lo = lane & 15, kgrp = lane >> 4;
    const int rowbase = blockIdx.x * 64 + wave * 16;

    const int arow0 = rowbase + (lane & 15);
    const int arow = arow0 < N ? arow0 : N - 1;     // clamp tail rows
    const float* xrow = X + (size_t)arow * 256 + kgrp * 8;

    // 1. issue all 16 X loads up front (drain during prep/spin)
    f32x4 a0[8], a1[8];
#pragma unroll
    for (int kc = 0; kc < 8; ++kc) {
        a0[kc] = *(const f32x4*)(xrow + kc * 32);
        a1[kc] = *(const f32x4*)(xrow + kc * 32 + 4);
    }

    // 2. prep blocks publish their Bf slice (device-scope release)
    if (blockIdx.x < npre) {
        prep_slice(blockIdx.x * 256 + t, Wv, bv, Bf, bm);
        __threadfence();
        __syncthreads();
        if (t == 0)
            __hip_atomic_fetch_add(flag, 1u, __ATOMIC_RELEASE, __HIP_MEMORY_SCOPE_AGENT);
    }

    // 3. wait for all 64 prep slices (acquire); most blocks launch after
    //    prep completed and pass immediately.
    if (t == 0) {
        while (__hip_atomic_load(flag, __ATOMIC_ACQUIRE, __HIP_MEMORY_SCOPE_AGENT) < NPREP)
            __builtin_amdgcn_s_sleep(2);
    }
    __syncthreads();

    // bias regs (L2-hot)
    float bias[4];
#pragma unroll
    for (int ct = 0; ct < 4; ++ct) bias[ct] = bm[ct * 16 + col_lo];

    // 4. MFMA loop, B fragments from global/L2
    f32x4 acc[4] = {};
#pragma unroll
    for (int kc = 0; kc < 8; ++kc) {
        short8 a;
        a[0] = (short)f2bf(a0[kc][0]); a[1] = (short)f2bf(a0[kc][1]);
        a[2] = (short)f2bf(a0[kc][2]); a[3] = (short)f2bf(a0[kc][3]);
        a[4] = (short)f2bf(a1[kc][0]); a[5] = (short)f2bf(a1[kc][1]);
        a[6] = (short)f2bf(a1[kc][2]); a[7] = (short)f2bf(a1[kc][3]);
#pragma unroll
        for (int ct = 0; ct < 4; ++ct) {
            const short8 b = *(const short8*)&Bf[((ct * 8 + kc) * 64 + lane) * 8];
            acc[ct] = __builtin_amdgcn_mfma_f32_16x16x32_bf16(a, b, acc[ct], 0, 0, 0);
        }
    }

    // 5. epilogue A: acc -> LDS (C/D: col=lane&15, row=(lane>>4)*4+reg)
    float* wtile = &Xt[wave][0];
#pragma unroll
    for (int ct = 0; ct < 4; ++ct) {
#pragma unroll
        for (int r = 0; r < 4; ++r)
            wtile[(kgrp * 4 + r) * 68 + ct * 16 + col_lo] = acc[ct][r] + bias[ct];
    }
    // same-wave LDS dependency only (no barrier)

    // epilogue B: instr s = rows [s*4,s*4+4) x all 64 cols = contiguous 1 KB
#pragma unroll
    for (int s = 0; s < 4; ++s) {
        const int rho = s * 4 + (lane >> 4);
        const int c4 = lane & 15;
        const f32x4 v = *(const f32x4*)&wtile[rho * 68 + c4 * 4];
        const int grow = rowbase + rho;
        if (grow < N)
            *(f32x4*)&out[(size_t)grow * 64 + c4 * 4] = v;
    }
}

extern "C" void kernel_launch(void* const* d_in, const int* in_sizes, int n_in,
                              void* d_out, int out_size, void* d_ws, size_t ws_size,
                              hipStream_t stream)
{
    const float* sx = (const float*)d_in[1];        // source_input
    const float* Wv = (const float*)d_in[6];
    const float* bv = (const float*)d_in[7];
    float* out = (float*)d_out;

    unsigned short* Bf = (unsigned short*)d_ws;                 // 32 KB
    float* bm = (float*)((char*)d_ws + 32768);                  // 256 B
    unsigned* flag = (unsigned*)((char*)d_ws + 33024);          // 4 B

    const int N = in_sizes[0] / 256;
    const int nblk = (N + 63) / 64;

    hipMemsetAsync(flag, 0, sizeof(unsigned), stream);          // poison-proof reset
    if (nblk >= NPREP) {
        k_main<<<nblk, 256, 0, stream>>>(sx, Wv, bv, Bf, bm, flag, out, N, NPREP);
    } else {
        k_prep<<<NPREP, 256, 0, stream>>>(Wv, bv, Bf, bm, flag);
        k_main<<<nblk, 256, 0, stream>>>(sx, Wv, bv, Bf, bm, flag, out, N, 0);
    }
}

// Round 13
// 32.956 us; speedup vs baseline: 2.2266x; 2.2266x over previous
//
#include <hip/hip_runtime.h>
#include <hip/hip_bf16.h>

typedef short short8 __attribute__((ext_vector_type(8)));
typedef float f32x4 __attribute__((ext_vector_type(4)));

__device__ inline unsigned short f2bf(float f) {
    unsigned u = __builtin_bit_cast(unsigned, f);
    u += 0x7FFFu + ((u >> 16) & 1u);          // round-to-nearest-even
    return (unsigned short)(u >> 16);
}

__device__ inline void gload_lds16(const void* g, void* l) {
    __builtin_amdgcn_global_load_lds(
        (const __attribute__((address_space(1))) void*)g,
        (__attribute__((address_space(3))) void*)l, 16, 0, 0);
}

// ---------------------------------------------------------------------------
// prep: Wm[d][c] = 0.25 * sum_h Wv[h*64+d][c], packed in MFMA B-fragment order
// (proven R2-R10). bm[d] = 0.25 * sum_h bv[h*64+d].
// ---------------------------------------------------------------------------
__global__ __launch_bounds__(256)
void k_prep(const float* __restrict__ Wv, const float* __restrict__ bv,
            unsigned short* __restrict__ Bf, float* __restrict__ bm)
{
    const int t = blockIdx.x * 256 + threadIdx.x;   // 0..16383
    const int fi = t >> 9;
    const int lane = (t >> 3) & 63;
    const int j = t & 7;
    const int ct = fi >> 3, kc = fi & 7;
    const int d = ct * 16 + (lane & 15);
    const int c = kc * 32 + (lane >> 4) * 8 + j;
    const float s = 0.25f * (Wv[(size_t)d * 256 + c] +
                             Wv[(size_t)(64 + d) * 256 + c] +
                             Wv[(size_t)(128 + d) * 256 + c] +
                             Wv[(size_t)(192 + d) * 256 + c]);
    Bf[t] = f2bf(s);
    if (t < 64)
        bm[t] = 0.25f * (bv[t] + bv[64 + t] + bv[128 + t] + bv[192 + t]);
}

// ---------------------------------------------------------------------------
// main: counted-vmcnt double-buffered pipeline (T3/T4-lite).
// Block = 256 thr / 4 waves, tile = 16 rows. LDS = 2 x 16KB fp32 X-buffers.
// Per tile: each wave issues 4 global_load_lds (1 KB each) for the NEXT tile,
// then vmcnt(4) (current tile's 4 done, next 4 stay in flight) + raw
// s_barrier -> 16 KB/block always outstanding, 5 blocks/CU = 80 KB/CU >> BDP.
// Wave w computes col-tile ct=w: B fragments (8 x short8) in registers.
// X staged with R8's verified source-side XOR swizzle (chunk ^ (row&7)<<4).
// Grid-stride persistent blocks (no churn ramp).
// ---------------------------------------------------------------------------
__global__ __launch_bounds__(256)
void k_main(const float* __restrict__ X, const unsigned short* __restrict__ Bf,
            const float* __restrict__ bm, float* __restrict__ out,
            int N, int ntiles)
{
    __shared__ float Xb[2][16][256];                // 32 KB

    const int t = threadIdx.x;
    const int wave = t >> 6, lane = t & 63;
    const int r = lane & 15, kgrp = lane >> 4;

    // per-wave B fragments (ct = wave) + bias, loaded once
    short8 bfr[8];
#pragma unroll
    for (int kc = 0; kc < 8; ++kc)
        bfr[kc] = *(const short8*)&Bf[((wave * 8 + kc) * 64 + lane) * 8];
    const float bias = bm[wave * 16 + r];

    asm volatile("s_waitcnt vmcnt(0)" ::: "memory"); // retire B/bias -> clean count

    int tile = blockIdx.x;
    if (tile >= ntiles) return;                     // whole block exits (uniform)

    // prologue: stage tile -> buf 0 (4 gload_lds per wave, rows wave*4..+3)
#pragma unroll
    for (int j = 0; j < 4; ++j) {
        const int i = wave * 4 + j;
        int row = tile * 16 + i;
        if (row >= N) row = N - 1;
        const char* src = (const char*)(X + (size_t)row * 256)
                        + ((lane * 16) ^ ((i & 7) << 4));
        gload_lds16(src, (char*)&Xb[0][i][0]);
    }

    int cur = 0;
    for (; tile < ntiles; tile += gridDim.x) {
        const int nxt_tile = tile + gridDim.x;
        if (nxt_tile < ntiles) {
            // stage next tile into the other buffer (outstanding -> 8)
#pragma unroll
            for (int j = 0; j < 4; ++j) {
                const int i = wave * 4 + j;
                int row = nxt_tile * 16 + i;
                if (row >= N) row = N - 1;
                const char* src = (const char*)(X + (size_t)row * 256)
                                + ((lane * 16) ^ ((i & 7) << 4));
                gload_lds16(src, (char*)&Xb[cur ^ 1][i][0]);
            }
            asm volatile("s_waitcnt vmcnt(4)" ::: "memory"); // cur's 4 done
        } else {
            asm volatile("s_waitcnt vmcnt(0)" ::: "memory"); // last tile: drain
        }
        __builtin_amdgcn_sched_barrier(0);
        __builtin_amdgcn_s_barrier();               // cur buffer visible to all

        // compute: A from LDS (swizzled), B from registers
        const char* rbase = (const char*)&Xb[cur][r][0];
        const int rx = (r & 7) << 4;
        f32x4 acc = {};
#pragma unroll
        for (int kc = 0; kc < 8; ++kc) {
            const int g0 = kgrp * 32 + kc * 128;
            const f32x4 x0 = *(const f32x4*)(rbase + ((g0) ^ rx));
            const f32x4 x1 = *(const f32x4*)(rbase + ((g0 + 16) ^ rx));
            short8 a;
            a[0] = (short)f2bf(x0[0]); a[1] = (short)f2bf(x0[1]);
            a[2] = (short)f2bf(x0[2]); a[3] = (short)f2bf(x0[3]);
            a[4] = (short)f2bf(x1[0]); a[5] = (short)f2bf(x1[1]);
            a[6] = (short)f2bf(x1[2]); a[7] = (short)f2bf(x1[3]);
            acc = __builtin_amdgcn_mfma_f32_16x16x32_bf16(a, bfr[kc], acc, 0, 0, 0);
        }

        // stores: C/D layout col=lane&15, row=(lane>>4)*4+reg [m89]
        const int rowb = tile * 16 + kgrp * 4;
        const int col = wave * 16 + r;
#pragma unroll
        for (int j = 0; j < 4; ++j) {
            const int row = rowb + j;
            if (row < N)
                out[(size_t)row * 64 + col] = acc[j] + bias;
        }

        __builtin_amdgcn_s_barrier();               // all reads done before
        cur ^= 1;                                   // buf[cur^1] is overwritten
    }
}

extern "C" void kernel_launch(void* const* d_in, const int* in_sizes, int n_in,
                              void* d_out, int out_size, void* d_ws, size_t ws_size,
                              hipStream_t stream)
{
    const float* sx = (const float*)d_in[1];        // source_input
    const float* Wv = (const float*)d_in[6];
    const float* bv = (const float*)d_in[7];
    float* out = (float*)d_out;

    unsigned short* Bf = (unsigned short*)d_ws;                 // 32 KB
    float* bm = (float*)((char*)d_ws + 32768);                  // 256 B

    const int N = in_sizes[0] / 256;
    const int ntiles = (N + 15) / 16;
    const int nblk = ntiles < 1280 ? ntiles : 1280; // 5 blocks/CU persistent

    k_prep<<<64, 256, 0, stream>>>(Wv, bv, Bf, bm);
    k_main<<<nblk, 256, 0, stream>>>(sx, Bf, bm, out, N, ntiles);
}